// Round 3
// baseline (261.446 us; speedup 1.0000x reference)
//
#include <hip/hip_runtime.h>
#include <hip/hip_bf16.h>
#include <math.h>

typedef _Float16 f16x4 __attribute__((ext_vector_type(4)));
typedef _Float16 f16x8 __attribute__((ext_vector_type(8)));
typedef float f32x4 __attribute__((ext_vector_type(4)));

#define DIM 128
#define LDST 136   // padded LDS row stride in f16 elems (272B, 16B-aligned, 2-way-free frag reads)

// ---------------------------------------------------------------------------
// Kernel 1: transpose + f16-convert the three 128x128 weight matrices.
// Wt[which][n][k] = (f16) W[k][n]  -> MFMA B-fragment reads become 16B loads.
// ---------------------------------------------------------------------------
__global__ __launch_bounds__(256) void prep_w_kernel(
    const float* __restrict__ Wq, const float* __restrict__ Wk,
    const float* __restrict__ Wv, _Float16* __restrict__ Wt)
{
    const float* W = (blockIdx.y == 0) ? Wq : (blockIdx.y == 1) ? Wk : Wv;
    _Float16* dst = Wt + (size_t)blockIdx.y * DIM * DIM;
    int idx = blockIdx.x * 256 + threadIdx.x;
    int k = idx >> 7;
    int n = idx & 127;
    dst[n * DIM + k] = (_Float16)W[idx];
}

// ---------------------------------------------------------------------------
// Kernel 2: CSR row_ptr from sorted rows[] via per-row lower_bound.
// ---------------------------------------------------------------------------
__global__ __launch_bounds__(256) void row_ptr_kernel(
    const int* __restrict__ rows, int* __restrict__ row_ptr, int n, int e)
{
    int r = blockIdx.x * 256 + threadIdx.x;
    if (r > n) return;
    if (r == n) { row_ptr[n] = e; return; }
    int lo = 0, hi = e;
    while (lo < hi) {
        int mid = (lo + hi) >> 1;
        if (rows[mid] < r) lo = mid + 1; else hi = mid;
    }
    row_ptr[r] = lo;
}

// ---------------------------------------------------------------------------
// Kernel 3: fused projection GEMM  Y = gelu(X @ W + b), output f16.
// Block = 256 thr (4 waves), tile 128 rows x 128 cols, K=128.
// A: coalesced float4 global loads -> f16 -> padded LDS -> ds_read_b128.
// B: global f16 Wt (L1-resident, 32KB).
// Epilogue: gelu -> LDS transpose -> 16B coalesced global stores.
// Output: which==0 -> qf[row*128]; which==1 -> kv[row*256] (k half);
//         which==2 -> kv[row*256+128] (v half)   [k|v interleaved per col]
// ---------------------------------------------------------------------------
__global__ __launch_bounds__(256, 2) void proj_gemm_kernel(
    const float* __restrict__ query, const float* __restrict__ memory,
    const _Float16* __restrict__ Wt,
    const float* __restrict__ bq, const float* __restrict__ bk,
    const float* __restrict__ bv,
    _Float16* __restrict__ qf, _Float16* __restrict__ kv, int n, int m)
{
    __shared__ _Float16 xs[128 * LDST];   // 34816 B

    int which = blockIdx.y;
    const float* X    = (which == 0) ? query : memory;
    const _Float16* Wm = Wt + (size_t)which * DIM * DIM;
    const float* bias = (which == 0) ? bq : (which == 1) ? bk : bv;
    int R             = (which == 0) ? n : m;
    _Float16* Ybase   = (which == 0) ? qf : (which == 2) ? kv + DIM : kv;
    size_t Ystride    = (which == 0) ? DIM : 2 * DIM;

    int tid = threadIdx.x;
    int rowblock = blockIdx.x * 128;
    if (rowblock >= R) return;

    // ---- stage X tile (fp32 -> f16) into LDS, coalesced ----
    for (int it = 0; it < 16; ++it) {
        int flat = it * 256 + tid;          // 4096 float4 chunks
        int r  = flat >> 5;                 // 0..127
        int c4 = (flat & 31) * 4;           // col (floats)
        int gr = rowblock + r;
        if (gr >= R) gr = R - 1;
        float4 x = *(const float4*)(X + (size_t)gr * DIM + c4);
        f16x4 w4;
        w4[0] = (_Float16)x.x; w4[1] = (_Float16)x.y;
        w4[2] = (_Float16)x.z; w4[3] = (_Float16)x.w;
        *(f16x4*)(&xs[r * LDST + c4]) = w4;
    }
    __syncthreads();

    int wave = tid >> 6;
    int lane = tid & 63;
    int quad = lane >> 4;
    int l16  = lane & 15;
    int wrow = wave * 32;   // wave's 32-row sub-tile

    // ---- A fragments from LDS (ds_read_b128, 2-way free) ----
    f16x8 afrag[2][4];
    for (int rt = 0; rt < 2; ++rt)
        for (int ks = 0; ks < 4; ++ks)
            afrag[rt][ks] = *(const f16x8*)(&xs[(wrow + rt * 16 + l16) * LDST + quad * 8 + ks * 32]);

    // ---- MFMA: 8 col-tiles x 2 row-tiles, K=128 ----
    f32x4 acc[8][2];
    for (int ct = 0; ct < 8; ++ct) { acc[ct][0] = {0,0,0,0}; acc[ct][1] = {0,0,0,0}; }
    for (int ct = 0; ct < 8; ++ct) {
        const _Float16* wp = Wm + (size_t)(ct * 16 + l16) * DIM + quad * 8;
        for (int ks = 0; ks < 4; ++ks) {
            f16x8 b = *(const f16x8*)(wp + ks * 32);
            acc[ct][0] = __builtin_amdgcn_mfma_f32_16x16x32_f16(afrag[0][ks], b, acc[ct][0], 0, 0, 0);
            acc[ct][1] = __builtin_amdgcn_mfma_f32_16x16x32_f16(afrag[1][ks], b, acc[ct][1], 0, 0, 0);
        }
    }

    // ---- epilogue: bias + gelu -> LDS (transpose) ----
    __syncthreads();
    for (int ct = 0; ct < 8; ++ct) {
        float bval = bias[ct * 16 + l16];
        for (int rt = 0; rt < 2; ++rt) {
            for (int reg = 0; reg < 4; ++reg) {
                float x = acc[ct][rt][reg] + bval;
                float t  = 0.7978845608028654f * (x + 0.044715f * x * x * x);
                float th = 1.0f - 2.0f / (__expf(2.0f * t) + 1.0f);
                float g  = 0.5f * x * (1.0f + th);
                xs[(wrow + rt * 16 + quad * 4 + reg) * LDST + ct * 16 + l16] = (_Float16)g;
            }
        }
    }
    __syncthreads();

    // ---- coalesced 16B stores ----
    for (int it = 0; it < 8; ++it) {
        int flat = it * 256 + tid;          // 2048 chunks of 8 f16
        int r  = flat >> 4;
        int c8 = (flat & 15) * 8;
        int gr = rowblock + r;
        if (gr < R) {
            f16x8 vv = *(const f16x8*)(&xs[r * LDST + c8]);
            *(f16x8*)(Ybase + (size_t)gr * Ystride + c8) = vv;
        }
    }
}

// ---------------------------------------------------------------------------
// Kernel 4: per-row edge attention, one wave per row, online softmax.
// quarter = lane>>4 picks 1 of 4 edge slots; l16 picks 8 dims (16B).
// k|v interleaved: one 512B record per col. 2x unrolled (8 edges in flight).
// (float)f16 in fma fuses to v_fma_mix_f32.
// ---------------------------------------------------------------------------
__global__ __launch_bounds__(256) void edge_attn_kernel(
    const _Float16* __restrict__ qf, const _Float16* __restrict__ kv,
    const float* __restrict__ adj_vals, const int* __restrict__ cols,
    const int* __restrict__ row_ptr, float* __restrict__ out, int n)
{
    int row = blockIdx.x * 4 + (threadIdx.x >> 6);
    if (row >= n) return;
    int lane    = threadIdx.x & 63;
    int quarter = lane >> 4;
    int l16     = lane & 15;

    int start = row_ptr[row];
    int end   = row_ptr[row + 1];

    float qv[8];
    {
        f16x8 qb = *(const f16x8*)(qf + (size_t)row * DIM + l16 * 8);
        for (int j = 0; j < 8; ++j) qv[j] = (float)qb[j];
    }

    float m_q = -1e30f, s_q = 0.0f;
    float acc[8];
    for (int j = 0; j < 8; ++j) acc[j] = 0.0f;

    const float scale = 0.08838834764831845f;   // 1/sqrt(128)

    for (int g = start; g < end; g += 8) {
        int eA = g + quarter;
        int eB = g + 4 + quarter;
        bool vA = eA < end;
        bool vB = eB < end;
        int   cA = vA ? cols[eA]     : 0;
        int   cB = vB ? cols[eB]     : 0;
        float aA = vA ? adj_vals[eA] : 0.0f;
        float aB = vB ? adj_vals[eB] : 0.0f;
        const _Float16* pA = kv + (size_t)cA * 256 + l16 * 8;
        const _Float16* pB = kv + (size_t)cB * 256 + l16 * 8;
        f16x8 kA = *(const f16x8*)pA;
        f16x8 vA8 = *(const f16x8*)(pA + 128);
        f16x8 kB = *(const f16x8*)pB;
        f16x8 vB8 = *(const f16x8*)(pB + 128);

        float dA = 0.0f, dB = 0.0f;
        for (int j = 0; j < 8; ++j) { dA += qv[j] * (float)kA[j]; dB += qv[j] * (float)kB[j]; }
        dA += __shfl_xor(dA, 1); dB += __shfl_xor(dB, 1);
        dA += __shfl_xor(dA, 2); dB += __shfl_xor(dB, 2);
        dA += __shfl_xor(dA, 4); dB += __shfl_xor(dB, 4);
        dA += __shfl_xor(dA, 8); dB += __shfl_xor(dB, 8);

        float sA = vA ? dA * aA * scale : -1e30f;
        float sB = vB ? dB * aB * scale : -1e30f;
        float m_new = fmaxf(m_q, fmaxf(sA, sB));
        float f  = __expf(m_q - m_new);          // m_q=-1e30 -> 0, no NaN
        float pA_ = vA ? __expf(sA - m_new) : 0.0f;
        float pB_ = vB ? __expf(sB - m_new) : 0.0f;
        s_q = s_q * f + pA_ + pB_;
        m_q = m_new;
        for (int j = 0; j < 8; ++j)
            acc[j] = acc[j] * f + pA_ * (float)vA8[j] + pB_ * (float)vB8[j];
    }

    // merge the 4 per-quarter online-softmax states
    float m_all = m_q;
    m_all = fmaxf(m_all, __shfl_xor(m_all, 16));
    m_all = fmaxf(m_all, __shfl_xor(m_all, 32));
    float f = __expf(m_q - m_all);
    float s_sc = s_q * f;
    s_sc += __shfl_xor(s_sc, 16);
    s_sc += __shfl_xor(s_sc, 32);
    float inv = (s_sc > 0.0f) ? 1.0f / s_sc : 0.0f;   // empty row -> zeros

    float o[8];
    for (int j = 0; j < 8; ++j) {
        float a = acc[j] * f;
        a += __shfl_xor(a, 16);
        a += __shfl_xor(a, 32);
        o[j] = a * inv;
    }
    if (quarter == 0) {
        float4* dst = (float4*)(out + (size_t)row * DIM + l16 * 8);
        dst[0] = make_float4(o[0], o[1], o[2], o[3]);
        dst[1] = make_float4(o[4], o[5], o[6], o[7]);
    }
}

// ---------------------------------------------------------------------------
extern "C" void kernel_launch(void* const* d_in, const int* in_sizes, int n_in,
                              void* d_out, int out_size, void* d_ws, size_t ws_size,
                              hipStream_t stream)
{
    const float* query    = (const float*)d_in[0];
    const float* memory   = (const float*)d_in[1];
    const float* adj_vals = (const float*)d_in[2];
    const float* Wq       = (const float*)d_in[3];
    const float* bq       = (const float*)d_in[4];
    const float* Wk       = (const float*)d_in[5];
    const float* bk       = (const float*)d_in[6];
    const float* Wv       = (const float*)d_in[7];
    const float* bv       = (const float*)d_in[8];
    const int*   rows     = (const int*)d_in[9];
    const int*   cols     = (const int*)d_in[10];
    float* out = (float*)d_out;

    int n = in_sizes[0] / DIM;   // 50000
    int m = in_sizes[1] / DIM;   // 50000
    int e = in_sizes[9];         // 1600000

    // workspace layout (16B-aligned)
    char* ws = (char*)d_ws;
    size_t off = 0;
    _Float16* Wt = (_Float16*)(ws + off); off += (size_t)3 * DIM * DIM * 2;    // 98304
    _Float16* qf = (_Float16*)(ws + off); off += (size_t)n * DIM * 2;          // 12.8MB
    _Float16* kv = (_Float16*)(ws + off); off += (size_t)m * 2 * DIM * 2;      // 25.6MB
    int* row_ptr = (int*)(ws + off);      off += (size_t)(n + 1) * 4;

    prep_w_kernel<<<dim3(64, 3), 256, 0, stream>>>(Wq, Wk, Wv, Wt);

    row_ptr_kernel<<<dim3((n + 1 + 255) / 256), 256, 0, stream>>>(rows, row_ptr, n, e);

    proj_gemm_kernel<<<dim3((n + 127) / 128, 3), 256, 0, stream>>>(
        query, memory, Wt, bq, bk, bv, qf, kv, n, m);

    edge_attn_kernel<<<dim3((n + 3) / 4), 256, 0, stream>>>(
        qf, kv, adj_vals, cols, row_ptr, out, n);
}